// Round 11
// baseline (838.446 us; speedup 1.0000x reference)
//
#include <hip/hip_runtime.h>
#include <hip/hip_fp16.h>
#include <stdint.h>

// ---------------------------------------------------------------------------
// Problem geometry (all compile-time):
//   x: (64, 48, 512, 2, 2) fp32. seq[s,n,f] = x[n, f>>2, 8*s, (f>>1)&1, f&1]
//   (only batch rows n<64 of the 512 matter downstream).
//   Layer1 BiGRU: in=192, H=256, 64 steps. Layer2 BiGRU: in=512, H=256.
//   Only final hiddens of layer2 used. dec_h = w_adj @ [hf,hb] + b_adj.
//   Decoder GRU (in=56, H=256) 6 steps, out = w_fc1@h + b_fc1 -> (64,6,56).
//
// SCAN ROOFLINE (r10 resolution of the r2-r10 residency saga): hipcc always
// streams the 393KB/step weight matrix from L2 (remats around every pin/AGPR
// trick). At 128 blocks = 16/XCD that stream is 6.3MB/step/XCD / 4.3TB/s =
// 1.46us/step = 94us/scan == measured. L2-BW-bound. Fix: 2 chains per block
// (chains of one dir share weights) -> traffic/chain halves; split-K thread
// shape (rows{tr,+256,+512} x K-half) keeps LDS h-reads at 32/thread
// (broadcast, reused across 3 gate rows). Expected ~0.85us/step.
// ---------------------------------------------------------------------------

#define HD 256
#define G3 768
#define NSEQ 64
#define NSTEP 64

typedef _Float16 hvec2 __attribute__((ext_vector_type(2)));
typedef _Float16 f16x8 __attribute__((ext_vector_type(8)));
typedef float f32x4 __attribute__((ext_vector_type(4)));

__device__ __forceinline__ float sigmf(float x) {
    return 1.0f / (1.0f + __expf(-x));
}

#if __has_builtin(__builtin_amdgcn_fdot2)
__device__ __forceinline__ float fdot2u(uint32_t w, uint32_t h, float acc) {
    return __builtin_amdgcn_fdot2(__builtin_bit_cast(hvec2, w),
                                  __builtin_bit_cast(hvec2, h), acc, false);
}
#else
__device__ __forceinline__ float fdot2u(uint32_t w, uint32_t h, float acc) {
    const __half2 wv = __builtin_bit_cast(__half2, w);
    const __half2 hv = __builtin_bit_cast(__half2, h);
    acc += __half2float(wv.x) * __half2float(hv.x);
    acc += __half2float(wv.y) * __half2float(hv.y);
    return acc;
}
#endif

__device__ __forceinline__ uint32_t pkh(float a, float b) {
    uint32_t lo = __half_as_ushort(__float2half_rn(a));
    uint32_t hi = __half_as_ushort(__float2half_rn(b));
    return lo | (hi << 16);
}

// ---------------- merged weight/input prep (one launch) ----------------
// Block ranges:
//   [0,480)      pack Whh (5 tensors x 96 blocks)
//   [480,768)    wih1f/wih1b fp32->f16 (144 blocks each)
//   [768,1536)   wih2f/wih2b fp32->f16 (384 blocks each)
//   [1536,2272)  small transposes (736)
//   [2272,5344)  gather seq -> f16 (3072)
__global__ __launch_bounds__(256) void prep_all(
    const float* __restrict__ whh1f, const float* __restrict__ whh1b,
    const float* __restrict__ whh2f, const float* __restrict__ whh2b,
    const float* __restrict__ whhd,
    uint32_t* __restrict__ wt1f, uint32_t* __restrict__ wt1b,
    uint32_t* __restrict__ wt2f, uint32_t* __restrict__ wt2b,
    uint32_t* __restrict__ wtd,
    const float* __restrict__ wih1f, const float* __restrict__ wih1b,
    const float* __restrict__ wih2f, const float* __restrict__ wih2b,
    __half* __restrict__ wih1f_h, __half* __restrict__ wih1b_h,
    __half* __restrict__ wih2f_h, __half* __restrict__ wih2b_h,
    const float* __restrict__ wihd, const float* __restrict__ wadj,
    const float* __restrict__ wfc1,
    float* __restrict__ wihdT, float* __restrict__ wadjT,
    float* __restrict__ wfc1T,
    const float* __restrict__ x, __half* __restrict__ seqg)
{
    const int b   = blockIdx.x;
    const int tid = threadIdx.x;

    if (b < 480) {
        // Whh repack -> uint4[q*768 + j], q=0..31 holds k=8q..8q+7 of row j
        const int y = b / 96;
        const float* w; uint32_t* o;
        switch (y) {
            case 0: w = whh1f; o = wt1f; break;
            case 1: w = whh1b; o = wt1b; break;
            case 2: w = whh2f; o = wt2f; break;
            case 3: w = whh2b; o = wt2b; break;
            default: w = whhd; o = wtd; break;
        }
        const int idx = (b % 96) * 256 + tid;   // 24576
        const int j = idx >> 5, q = idx & 31;
        const float4 fa = *(const float4*)(w + j * HD + 8 * q);
        const float4 fb = *(const float4*)(w + j * HD + 8 * q + 4);
        uint4 r;
        r.x = pkh(fa.x, fa.y); r.y = pkh(fa.z, fa.w);
        r.z = pkh(fb.x, fb.y); r.w = pkh(fb.z, fb.w);
        ((uint4*)o)[q * G3 + j] = r;
    } else if (b < 1536) {
        const float* s; __half* d; int i4;
        if (b < 624)       { s = wih1f; d = wih1f_h; i4 = (b - 480) * 256 + tid; }
        else if (b < 768)  { s = wih1b; d = wih1b_h; i4 = (b - 624) * 256 + tid; }
        else if (b < 1152) { s = wih2f; d = wih2f_h; i4 = (b - 768) * 256 + tid; }
        else               { s = wih2b; d = wih2b_h; i4 = (b - 1152) * 256 + tid; }
        const float4 v = *(const float4*)(s + (size_t)i4 * 4);
        __half2 lo; lo.x = __float2half_rn(v.x); lo.y = __float2half_rn(v.y);
        __half2 hi; hi.x = __float2half_rn(v.z); hi.y = __float2half_rn(v.w);
        *(__half2*)(d + (size_t)i4 * 4)     = lo;
        *(__half2*)(d + (size_t)i4 * 4 + 2) = hi;
    } else if (b < 2272) {
        const int idx = (b - 1536) * 256 + tid;  // 188416
        if (idx < 43008) {
            int v = idx / G3, j = idx % G3;
            wihdT[idx] = wihd[j * 56 + v];
        } else if (idx < 43008 + 131072) {
            int i2 = idx - 43008;
            int f = i2 / HD, i = i2 % HD;
            wadjT[i2] = wadj[i * 512 + f];
        } else {
            int i3 = idx - 174080;
            int k = i3 / 56, v = i3 % 56;
            wfc1T[i3] = wfc1[v * HD + k];
        }
    } else {
        const int idx = (b - 2272) * 256 + tid;  // 786432
        const int f = idx % 192;
        const int m = idx / 192;
        const int n = m >> 6, s = m & 63;
        seqg[idx] = __float2half(
            x[n * 98304 + (f >> 2) * 2048 + s * 32 + (f & 3)]);
    }
}

// ---------------- f16 MFMA GEMM with bias ----------------
// C[m][j] = sum_k A[m][k]*B[j][k] + bias[j]; M=4096, N=768, K in {192,512}.
// grid=(64, 12, 2); block = 4 waves; wave w computes rows m0+16w..+16,
// cols n0..n0+63 as 4 accumulators. No LDS: operands are L2-resident.
// C/D layout (HW-verified): col=lane&15, row=(lane>>4)*4+reg.
__global__ __launch_bounds__(256) void gemm_mfma(
    const __half* __restrict__ A,
    const __half* __restrict__ B0, const __half* __restrict__ B1,
    const float* __restrict__ bias0, const float* __restrict__ bias1,
    float* __restrict__ C0, float* __restrict__ C1, int K)
{
    const __half* B    = blockIdx.z ? B1 : B0;
    const float*  bias = blockIdx.z ? bias1 : bias0;
    float*        C    = blockIdx.z ? C1 : C0;
    const int m0 = blockIdx.x * 64;
    const int n0 = blockIdx.y * 64;
    const int w  = threadIdx.x >> 6;
    const int l  = threadIdx.x & 63;
    const int lr = l & 15;
    const int lk = (l >> 4) * 8;

    const __half* arow = A + (size_t)(m0 + w * 16 + lr) * K + lk;
    const __half* brow = B + (size_t)(n0 + lr) * K + lk;

    f32x4 acc0 = {0.f, 0.f, 0.f, 0.f};
    f32x4 acc1 = acc0, acc2 = acc0, acc3 = acc0;

#pragma unroll 2
    for (int k0 = 0; k0 < K; k0 += 32) {
        const f16x8 a  = *(const f16x8*)(arow + k0);
        const f16x8 b0 = *(const f16x8*)(brow + k0);
        const f16x8 b1 = *(const f16x8*)(brow + 16 * K + k0);
        const f16x8 b2 = *(const f16x8*)(brow + 32 * K + k0);
        const f16x8 b3 = *(const f16x8*)(brow + 48 * K + k0);
        acc0 = __builtin_amdgcn_mfma_f32_16x16x32_f16(a, b0, acc0, 0, 0, 0);
        acc1 = __builtin_amdgcn_mfma_f32_16x16x32_f16(a, b1, acc1, 0, 0, 0);
        acc2 = __builtin_amdgcn_mfma_f32_16x16x32_f16(a, b2, acc2, 0, 0, 0);
        acc3 = __builtin_amdgcn_mfma_f32_16x16x32_f16(a, b3, acc3, 0, 0, 0);
    }

    const int crow = m0 + w * 16 + (l >> 4) * 4;
    const int ccol = n0 + lr;
    float* cp = C + (size_t)crow * G3 + ccol;
    const float bb0 = bias[ccol];
    const float bb1 = bias[ccol + 16];
    const float bb2 = bias[ccol + 32];
    const float bb3 = bias[ccol + 48];
#pragma unroll
    for (int j = 0; j < 4; ++j) {
        cp[(size_t)j * G3 +  0] = acc0[j] + bb0;
        cp[(size_t)j * G3 + 16] = acc1[j] + bb1;
        cp[(size_t)j * G3 + 32] = acc2[j] + bb2;
        cp[(size_t)j * G3 + 48] = acc3[j] + bb3;
    }
}

// ---------------- GRU scan: 2 chains/block, split-K, streamed weights ------
// grid = 64 blocks: dir = blockIdx.x&1, np = blockIdx.x>>1 -> chains
// {2np, 2np+1} of that direction. 512 threads: thread (kh=t>>8, tr=t&255)
// owns gate rows {tr,256+tr,512+tr} for K-half kh. Each streamed weight
// uint4 feeds BOTH chains (halves L2 traffic/chain). Partial exchange is
// symmetric: kh0 publishes chain-B partials, kh1 publishes chain-A; then
// kh0 lanes run chain-A gates, kh1 lanes chain-B gates.
__global__ __launch_bounds__(512, 1) void gru_scan(
    const float* __restrict__ giF, const float* __restrict__ giB,
    const uint32_t* __restrict__ wTF, const uint32_t* __restrict__ wTB,
    const float* __restrict__ bhhF, const float* __restrict__ bhhB,
    __half* __restrict__ y1h, float* __restrict__ hfin)
{
    const int dir = blockIdx.x & 1;
    const int np  = blockIdx.x >> 1;          // 0..31
    const int t   = threadIdx.x;
    const int tr  = t & 255;
    const int kh  = t >> 8;                   // K-half
    const int hoff = kh * 64;                 // u32 offset into h buffers
    const float* gi  = dir ? giB : giF;
    const float* bhh = dir ? bhhB : bhhF;
    const uint4* wq  = (const uint4*)(dir ? wTB : wTF) + (size_t)(kh * 16) * G3;

    __shared__ __align__(16) uint32_t hA[2][HD / 2], hB[2][HD / 2];
    __shared__ float phA_r[HD], phA_z[HD], phA_n[HD];   // written by kh=1
    __shared__ float phB_r[HD], phB_z[HD], phB_n[HD];   // written by kh=0

    const float bhr = bhh[tr], bhz = bhh[256 + tr], bhn = bhh[512 + tr];

    // gate-phase chain: kh==0 -> chain A (n=2np), kh==1 -> chain B (n=2np+1)
    const int n_mine = np * 2 + kh;
    const float* gb_mine = gi + (size_t)n_mine * NSTEP * G3;

    if (t < HD / 2) { hA[0][t] = 0u; hB[0][t] = 0u; }
    __syncthreads();

    int s = dir ? (NSTEP - 1) : 0;
    float g_r = gb_mine[s * G3 + tr];
    float g_z = gb_mine[s * G3 + 256 + tr];
    float g_n = gb_mine[s * G3 + 512 + tr];
    float h_own = 0.0f;

    for (int step = 0; step < NSTEP; ++step) {
        const int s_nxt = dir ? (step < NSTEP - 1 ? NSTEP - 2 - step : 0)
                              : (step < NSTEP - 1 ? step + 1 : NSTEP - 1);
        const float gn_r = gb_mine[s_nxt * G3 + tr];
        const float gn_z = gb_mine[s_nxt * G3 + 256 + tr];
        const float gn_n = gb_mine[s_nxt * G3 + 512 + tr];

        const uint32_t* ha = hA[step & 1];
        const uint32_t* hb = hB[step & 1];
        float arA0 = 0.f, arA1 = 0.f, azA0 = 0.f, azA1 = 0.f;
        float anA0 = 0.f, anA1 = 0.f;
        float arB0 = 0.f, arB1 = 0.f, azB0 = 0.f, azB1 = 0.f;
        float anB0 = 0.f, anB1 = 0.f;
#pragma unroll
        for (int i = 0; i < 16; ++i) {
            const uint4 wr_ = wq[i * G3 + tr];
            const uint4 wz_ = wq[i * G3 + 256 + tr];
            const uint4 wn_ = wq[i * G3 + 512 + tr];
            const uint4 pA = *(const uint4*)&ha[hoff + 4 * i];
            const uint4 pB = *(const uint4*)&hb[hoff + 4 * i];
            arA0 = fdot2u(wr_.x, pA.x, arA0); arA1 = fdot2u(wr_.y, pA.y, arA1);
            arA0 = fdot2u(wr_.z, pA.z, arA0); arA1 = fdot2u(wr_.w, pA.w, arA1);
            azA0 = fdot2u(wz_.x, pA.x, azA0); azA1 = fdot2u(wz_.y, pA.y, azA1);
            azA0 = fdot2u(wz_.z, pA.z, azA0); azA1 = fdot2u(wz_.w, pA.w, azA1);
            anA0 = fdot2u(wn_.x, pA.x, anA0); anA1 = fdot2u(wn_.y, pA.y, anA1);
            anA0 = fdot2u(wn_.z, pA.z, anA0); anA1 = fdot2u(wn_.w, pA.w, anA1);
            arB0 = fdot2u(wr_.x, pB.x, arB0); arB1 = fdot2u(wr_.y, pB.y, arB1);
            arB0 = fdot2u(wr_.z, pB.z, arB0); arB1 = fdot2u(wr_.w, pB.w, arB1);
            azB0 = fdot2u(wz_.x, pB.x, azB0); azB1 = fdot2u(wz_.y, pB.y, azB1);
            azB0 = fdot2u(wz_.z, pB.z, azB0); azB1 = fdot2u(wz_.w, pB.w, azB1);
            anB0 = fdot2u(wn_.x, pB.x, anB0); anB1 = fdot2u(wn_.y, pB.y, anB1);
            anB0 = fdot2u(wn_.z, pB.z, anB0); anB1 = fdot2u(wn_.w, pB.w, anB1);
        }
        if (kh == 0) {
            phB_r[tr] = arB0 + arB1;
            phB_z[tr] = azB0 + azB1;
            phB_n[tr] = anB0 + anB1;
        } else {
            phA_r[tr] = arA0 + arA1;
            phA_z[tr] = azA0 + azA1;
            phA_n[tr] = anA0 + anA1;
        }
        __syncthreads();
        {
            const float mr = kh ? (arB0 + arB1) + phB_r[tr]
                                : (arA0 + arA1) + phA_r[tr];
            const float mz = kh ? (azB0 + azB1) + phB_z[tr]
                                : (azA0 + azA1) + phA_z[tr];
            const float mn = kh ? (anB0 + anB1) + phB_n[tr]
                                : (anA0 + anA1) + phA_n[tr];
            const float r  = sigmf(g_r + mr + bhr);
            const float z  = sigmf(g_z + mz + bhz);
            const float nn = tanhf(g_n + r * (mn + bhn));
            const float hnew = (1.0f - z) * nn + z * h_own;
            h_own = hnew;
            uint32_t* hnx = kh ? hB[(step + 1) & 1] : hA[(step + 1) & 1];
            ((__half*)hnx)[tr] = __float2half(hnew);
            y1h[(size_t)(n_mine * NSTEP + s) * 512 + dir * HD + tr] =
                __float2half(hnew);
        }
        g_r = gn_r; g_z = gn_z; g_n = gn_n;
        s = s_nxt;
        __syncthreads();
    }
    hfin[(size_t)(dir * NSEQ + n_mine) * HD + tr] = h_own;
}

// ---------------- dec_h = w_adj @ [hf,hb] + b_adj ----------------
__global__ __launch_bounds__(256) void adj_kernel(
    const float* __restrict__ hfin, const float* __restrict__ wadjT,
    const float* __restrict__ badj, float* __restrict__ dech)
{
    const int n = blockIdx.x, t = threadIdx.x;
    __shared__ float comb[512];
    comb[t]      = hfin[(size_t)n * HD + t];
    comb[HD + t] = hfin[(size_t)(NSEQ + n) * HD + t];
    __syncthreads();
    float acc = badj[t];
#pragma unroll 8
    for (int f = 0; f < 512; ++f) acc += wadjT[f * HD + t] * comb[f];
    dech[n * HD + t] = acc;
}

// ---------------- decoder: 64 blocks x 768 threads, streamed weights -------
__global__ __launch_bounds__(768, 3) void decoder_kernel(
    const float* __restrict__ dech, const uint32_t* __restrict__ wTd,
    const float* __restrict__ wihdT, const float* __restrict__ bihd,
    const float* __restrict__ bhhd, const float* __restrict__ wfc1T,
    const float* __restrict__ bfc1, float* __restrict__ out)
{
    const int n = blockIdx.x, t = threadIdx.x;
    const uint4* wq = (const uint4*)wTd + t;

    __shared__ __align__(16) uint32_t h1u[2][HD / 2];
    __shared__ float ghs[G3], gis[G3];
    __shared__ float hfp[HD];
    __shared__ float inp[56];
    __shared__ float pf1[448];

    const float bi = bihd[t], bh = bhhd[t];

    float h_own = 0.0f;
    if (t < HD) {
        const float hv = dech[(size_t)n * HD + t];
        h_own = hv;
        ((__half*)h1u[0])[t] = __float2half(hv);
        hfp[t] = hv;
    }
    if (t < 56) inp[t] = 0.0f;
    __syncthreads();

    for (int step = 0; step < 6; ++step) {
        const uint32_t* hb = h1u[step & 1];
        float a0 = 0.f, a1 = 0.f;
#pragma unroll 8
        for (int q = 0; q < 32; ++q) {
            const uint4 w = wq[q * G3];
            const uint4 hp = *(const uint4*)&hb[4 * q];
            a0 = fdot2u(w.x, hp.x, a0); a1 = fdot2u(w.y, hp.y, a1);
            a0 = fdot2u(w.z, hp.z, a0); a1 = fdot2u(w.w, hp.w, a1);
        }
        float ai = bi;
#pragma unroll 8
        for (int v = 0; v < 56; ++v) ai += wihdT[v * G3 + t] * inp[v];
        ghs[t] = a0 + a1 + bh;
        gis[t] = ai;
        __syncthreads();
        if (t < HD) {
            const float r  = sigmf(gis[t] + ghs[t]);
            const float z  = sigmf(gis[HD + t] + ghs[HD + t]);
            const float nn = tanhf(gis[2 * HD + t] + r * ghs[2 * HD + t]);
            const float hnew = (1.0f - z) * nn + z * h_own;
            h_own = hnew;
            ((__half*)h1u[(step + 1) & 1])[t] = __float2half(hnew);
            hfp[t] = hnew;
        }
        __syncthreads();
        if (t < 448) {
            const int v = t >> 3, g = t & 7;
            float o = 0.f;
#pragma unroll
            for (int k2 = 0; k2 < 32; ++k2)
                o += wfc1T[(g * 32 + k2) * 56 + v] * hfp[g * 32 + k2];
            pf1[t] = o;
        }
        __syncthreads();
        if (t < 56) {
            float o = bfc1[t];
#pragma unroll
            for (int g = 0; g < 8; ++g) o += pf1[t * 8 + g];
            out[(size_t)n * 336 + step * 56 + t] = o;
            inp[t] = o;
        }
        __syncthreads();
    }
}

// ---------------------------------------------------------------------------
extern "C" void kernel_launch(void* const* d_in, const int* in_sizes, int n_in,
                              void* d_out, int out_size, void* d_ws, size_t ws_size,
                              hipStream_t stream)
{
    const float* x      = (const float*)d_in[0];
    const float* wih1f  = (const float*)d_in[1];
    const float* whh1f  = (const float*)d_in[2];
    const float* bih1f  = (const float*)d_in[3];
    const float* bhh1f  = (const float*)d_in[4];
    const float* wih1b  = (const float*)d_in[5];
    const float* whh1b  = (const float*)d_in[6];
    const float* bih1b  = (const float*)d_in[7];
    const float* bhh1b  = (const float*)d_in[8];
    const float* wih2f  = (const float*)d_in[9];
    const float* whh2f  = (const float*)d_in[10];
    const float* bih2f  = (const float*)d_in[11];
    const float* bhh2f  = (const float*)d_in[12];
    const float* wih2b  = (const float*)d_in[13];
    const float* whh2b  = (const float*)d_in[14];
    const float* bih2b  = (const float*)d_in[15];
    const float* bhh2b  = (const float*)d_in[16];
    const float* wihd   = (const float*)d_in[17];
    const float* whhd   = (const float*)d_in[18];
    const float* bihd   = (const float*)d_in[19];
    const float* bhhd   = (const float*)d_in[20];
    const float* wfc1   = (const float*)d_in[21];
    const float* bfc1   = (const float*)d_in[22];
    const float* wadj   = (const float*)d_in[23];
    const float* badj   = (const float*)d_in[24];

    float* ws = (float*)d_ws;
    __half*   seqg_h  = (__half*)(ws + 0);           // 786432 f16
    float*    gi_f    = ws + 393216;                 // 3145728
    float*    gi_b    = ws + 3538944;                // 3145728
    __half*   y1h     = (__half*)(ws + 6684672);     // 2097152 f16
    float*    hfin    = ws + 7733248;                // 32768
    float*    dech    = ws + 7766016;                // 16384
    uint32_t* wt1f    = (uint32_t*)(ws + 7782400);   // 98304 each
    uint32_t* wt1b    = (uint32_t*)(ws + 7880704);
    uint32_t* wt2f    = (uint32_t*)(ws + 7979008);
    uint32_t* wt2b    = (uint32_t*)(ws + 8077312);
    uint32_t* wtd     = (uint32_t*)(ws + 8175616);
    __half*   wih1f_h = (__half*)(ws + 8273920);     // 147456 f16
    __half*   wih1b_h = (__half*)(ws + 8347648);
    __half*   wih2f_h = (__half*)(ws + 8421376);     // 393216 f16
    __half*   wih2b_h = (__half*)(ws + 8617984);
    float*    wihdT   = ws + 8814592;                // 43008
    float*    wadjT   = ws + 8857600;                // 131072
    float*    wfc1T   = ws + 8988672;                // 14336

    prep_all<<<5344, 256, 0, stream>>>(
        whh1f, whh1b, whh2f, whh2b, whhd,
        wt1f, wt1b, wt2f, wt2b, wtd,
        wih1f, wih1b, wih2f, wih2b,
        wih1f_h, wih1b_h, wih2f_h, wih2b_h,
        wihd, wadj, wfc1, wihdT, wadjT, wfc1T,
        x, seqg_h);

    // layer 1
    gemm_mfma<<<dim3(64, 12, 2), 256, 0, stream>>>(
        seqg_h, wih1f_h, wih1b_h, bih1f, bih1b, gi_f, gi_b, 192);
    gru_scan<<<64, 512, 0, stream>>>(
        gi_f, gi_b, wt1f, wt1b, bhh1f, bhh1b, y1h, hfin);

    // layer 2 (gi buffers reused; scan2's y1h writes are dead but harmless)
    gemm_mfma<<<dim3(64, 12, 2), 256, 0, stream>>>(
        y1h, wih2f_h, wih2b_h, bih2f, bih2b, gi_f, gi_b, 512);
    gru_scan<<<64, 512, 0, stream>>>(
        gi_f, gi_b, wt2f, wt2b, bhh2f, bhh2b, y1h, hfin);

    // decoder head
    adj_kernel<<<64, 256, 0, stream>>>(hfin, wadjT, badj, dech);
    decoder_kernel<<<64, 768, 0, stream>>>(
        dech, wtd, wihdT, bihd, bhhd, wfc1T, bfc1, (float*)d_out);
}

// Round 12
// 409.002 us; speedup vs baseline: 2.0500x; 2.0500x over previous
//
#include <hip/hip_runtime.h>
#include <hip/hip_fp16.h>
#include <stdint.h>

// ---------------------------------------------------------------------------
// Problem geometry (all compile-time):
//   x: (64, 48, 512, 2, 2) fp32. seq[s,n,f] = x[n, f>>2, 8*s, (f>>1)&1, f&1]
//   (only batch rows n<64 of the 512 matter downstream).
//   Layer1 BiGRU: in=192, H=256, 64 steps. Layer2 BiGRU: in=512, H=256.
//   Only final hiddens of layer2 used. dec_h = w_adj @ [hf,hb] + b_adj.
//   Decoder GRU (in=56, H=256) 6 steps, out = w_fc1@h + b_fc1 -> (64,6,56).
//
// SCAN MODEL (r10/r11 resolution): hipcc always streams the weight matrix
// (remats around every residency trick, r2-r10 ledger). r10 measured
// 1.5us/step at 128 blocks = L2 aggregate ceiling (34TB/s) AND per-CU port
// (~113B/cyc) simultaneously. r11's 64-block 2-chain variant latency-starved
// (VALUBusy 7.7%). r12: keep r10's 768-thr/128-block shape, stage 12/32
// K-chunks (144KB) in dynamic LDS once -> stream only 245KB/step from L2
// (0.8us) overlapped with LDS weight reads (0.7us). Expect ~1us/step.
// r11's other finding: prep_all merge saved >100us of launch overhead. Keep.
// ---------------------------------------------------------------------------

#define HD 256
#define G3 768
#define NSEQ 64
#define NSTEP 64
#define LDS_CHUNKS 12     // K-chunks staged in LDS (of 32); 12*768*16B = 144KB

typedef _Float16 hvec2 __attribute__((ext_vector_type(2)));
typedef _Float16 f16x8 __attribute__((ext_vector_type(8)));
typedef float f32x4 __attribute__((ext_vector_type(4)));

__device__ __forceinline__ float sigmf(float x) {
    return 1.0f / (1.0f + __expf(-x));
}

#if __has_builtin(__builtin_amdgcn_fdot2)
__device__ __forceinline__ float fdot2u(uint32_t w, uint32_t h, float acc) {
    return __builtin_amdgcn_fdot2(__builtin_bit_cast(hvec2, w),
                                  __builtin_bit_cast(hvec2, h), acc, false);
}
#else
__device__ __forceinline__ float fdot2u(uint32_t w, uint32_t h, float acc) {
    const __half2 wv = __builtin_bit_cast(__half2, w);
    const __half2 hv = __builtin_bit_cast(__half2, h);
    acc += __half2float(wv.x) * __half2float(hv.x);
    acc += __half2float(wv.y) * __half2float(hv.y);
    return acc;
}
#endif

__device__ __forceinline__ uint32_t pkh(float a, float b) {
    uint32_t lo = __half_as_ushort(__float2half_rn(a));
    uint32_t hi = __half_as_ushort(__float2half_rn(b));
    return lo | (hi << 16);
}

// ---------------- merged weight/input prep (one launch) ----------------
// Block ranges:
//   [0,480)      pack Whh (5 tensors x 96 blocks)
//   [480,768)    wih1f/wih1b fp32->f16 (144 blocks each)
//   [768,1536)   wih2f/wih2b fp32->f16 (384 blocks each)
//   [1536,2272)  small transposes (736)
//   [2272,5344)  gather seq -> f16 (3072)
__global__ __launch_bounds__(256) void prep_all(
    const float* __restrict__ whh1f, const float* __restrict__ whh1b,
    const float* __restrict__ whh2f, const float* __restrict__ whh2b,
    const float* __restrict__ whhd,
    uint32_t* __restrict__ wt1f, uint32_t* __restrict__ wt1b,
    uint32_t* __restrict__ wt2f, uint32_t* __restrict__ wt2b,
    uint32_t* __restrict__ wtd,
    const float* __restrict__ wih1f, const float* __restrict__ wih1b,
    const float* __restrict__ wih2f, const float* __restrict__ wih2b,
    __half* __restrict__ wih1f_h, __half* __restrict__ wih1b_h,
    __half* __restrict__ wih2f_h, __half* __restrict__ wih2b_h,
    const float* __restrict__ wihd, const float* __restrict__ wadj,
    const float* __restrict__ wfc1,
    float* __restrict__ wihdT, float* __restrict__ wadjT,
    float* __restrict__ wfc1T,
    const float* __restrict__ x, __half* __restrict__ seqg)
{
    const int b   = blockIdx.x;
    const int tid = threadIdx.x;

    if (b < 480) {
        // Whh repack -> uint4[q*768 + j], q=0..31 holds k=8q..8q+7 of row j
        const int y = b / 96;
        const float* w; uint32_t* o;
        switch (y) {
            case 0: w = whh1f; o = wt1f; break;
            case 1: w = whh1b; o = wt1b; break;
            case 2: w = whh2f; o = wt2f; break;
            case 3: w = whh2b; o = wt2b; break;
            default: w = whhd; o = wtd; break;
        }
        const int idx = (b % 96) * 256 + tid;   // 24576
        const int j = idx >> 5, q = idx & 31;
        const float4 fa = *(const float4*)(w + j * HD + 8 * q);
        const float4 fb = *(const float4*)(w + j * HD + 8 * q + 4);
        uint4 r;
        r.x = pkh(fa.x, fa.y); r.y = pkh(fa.z, fa.w);
        r.z = pkh(fb.x, fb.y); r.w = pkh(fb.z, fb.w);
        ((uint4*)o)[q * G3 + j] = r;
    } else if (b < 1536) {
        const float* s; __half* d; int i4;
        if (b < 624)       { s = wih1f; d = wih1f_h; i4 = (b - 480) * 256 + tid; }
        else if (b < 768)  { s = wih1b; d = wih1b_h; i4 = (b - 624) * 256 + tid; }
        else if (b < 1152) { s = wih2f; d = wih2f_h; i4 = (b - 768) * 256 + tid; }
        else               { s = wih2b; d = wih2b_h; i4 = (b - 1152) * 256 + tid; }
        const float4 v = *(const float4*)(s + (size_t)i4 * 4);
        __half2 lo; lo.x = __float2half_rn(v.x); lo.y = __float2half_rn(v.y);
        __half2 hi; hi.x = __float2half_rn(v.z); hi.y = __float2half_rn(v.w);
        *(__half2*)(d + (size_t)i4 * 4)     = lo;
        *(__half2*)(d + (size_t)i4 * 4 + 2) = hi;
    } else if (b < 2272) {
        const int idx = (b - 1536) * 256 + tid;  // 188416
        if (idx < 43008) {
            int v = idx / G3, j = idx % G3;
            wihdT[idx] = wihd[j * 56 + v];
        } else if (idx < 43008 + 131072) {
            int i2 = idx - 43008;
            int f = i2 / HD, i = i2 % HD;
            wadjT[i2] = wadj[i * 512 + f];
        } else {
            int i3 = idx - 174080;
            int k = i3 / 56, v = i3 % 56;
            wfc1T[i3] = wfc1[v * HD + k];
        }
    } else {
        const int idx = (b - 2272) * 256 + tid;  // 786432
        const int f = idx % 192;
        const int m = idx / 192;
        const int n = m >> 6, s = m & 63;
        seqg[idx] = __float2half(
            x[n * 98304 + (f >> 2) * 2048 + s * 32 + (f & 3)]);
    }
}

// ---------------- f16 MFMA GEMM with bias ----------------
// C[m][j] = sum_k A[m][k]*B[j][k] + bias[j]; M=4096, N=768, K in {192,512}.
// grid=(64, 12, 2); block = 4 waves; wave w computes rows m0+16w..+16,
// cols n0..n0+63 as 4 accumulators. No LDS: operands are L2-resident.
// C/D layout (HW-verified): col=lane&15, row=(lane>>4)*4+reg.
__global__ __launch_bounds__(256) void gemm_mfma(
    const __half* __restrict__ A,
    const __half* __restrict__ B0, const __half* __restrict__ B1,
    const float* __restrict__ bias0, const float* __restrict__ bias1,
    float* __restrict__ C0, float* __restrict__ C1, int K)
{
    const __half* B    = blockIdx.z ? B1 : B0;
    const float*  bias = blockIdx.z ? bias1 : bias0;
    float*        C    = blockIdx.z ? C1 : C0;
    const int m0 = blockIdx.x * 64;
    const int n0 = blockIdx.y * 64;
    const int w  = threadIdx.x >> 6;
    const int l  = threadIdx.x & 63;
    const int lr = l & 15;
    const int lk = (l >> 4) * 8;

    const __half* arow = A + (size_t)(m0 + w * 16 + lr) * K + lk;
    const __half* brow = B + (size_t)(n0 + lr) * K + lk;

    f32x4 acc0 = {0.f, 0.f, 0.f, 0.f};
    f32x4 acc1 = acc0, acc2 = acc0, acc3 = acc0;

#pragma unroll 2
    for (int k0 = 0; k0 < K; k0 += 32) {
        const f16x8 a  = *(const f16x8*)(arow + k0);
        const f16x8 b0 = *(const f16x8*)(brow + k0);
        const f16x8 b1 = *(const f16x8*)(brow + 16 * K + k0);
        const f16x8 b2 = *(const f16x8*)(brow + 32 * K + k0);
        const f16x8 b3 = *(const f16x8*)(brow + 48 * K + k0);
        acc0 = __builtin_amdgcn_mfma_f32_16x16x32_f16(a, b0, acc0, 0, 0, 0);
        acc1 = __builtin_amdgcn_mfma_f32_16x16x32_f16(a, b1, acc1, 0, 0, 0);
        acc2 = __builtin_amdgcn_mfma_f32_16x16x32_f16(a, b2, acc2, 0, 0, 0);
        acc3 = __builtin_amdgcn_mfma_f32_16x16x32_f16(a, b3, acc3, 0, 0, 0);
    }

    const int crow = m0 + w * 16 + (l >> 4) * 4;
    const int ccol = n0 + lr;
    float* cp = C + (size_t)crow * G3 + ccol;
    const float bb0 = bias[ccol];
    const float bb1 = bias[ccol + 16];
    const float bb2 = bias[ccol + 32];
    const float bb3 = bias[ccol + 48];
#pragma unroll
    for (int j = 0; j < 4; ++j) {
        cp[(size_t)j * G3 +  0] = acc0[j] + bb0;
        cp[(size_t)j * G3 + 16] = acc1[j] + bb1;
        cp[(size_t)j * G3 + 32] = acc2[j] + bb2;
        cp[(size_t)j * G3 + 48] = acc3[j] + bb3;
    }
}

// ---------------- GRU scan: 768 thr, LDS-staged + streamed weights --------
// grid = 128 blocks: dir = blockIdx.x&1, n = blockIdx.x>>1.
// Thread t owns gate row t (full K=256): 32 K-chunks of uint4.
// Chunks 0..LDS_CHUNKS-1 staged once in dynamic LDS (144KB); chunks
// LDS_CHUNKS..31 streamed from L2 each step (245KB/step). The two weight
// paths (LDS port + L2 port) overlap -> ~1us/step vs 1.5 pure-stream (r10).
// h double-buffered f16x2 in LDS (broadcast reads); 2 barriers/step.
__global__ __launch_bounds__(768, 1) void gru_scan(
    const float* __restrict__ giF, const float* __restrict__ giB,
    const uint32_t* __restrict__ wTF, const uint32_t* __restrict__ wTB,
    const float* __restrict__ bhhF, const float* __restrict__ bhhB,
    __half* __restrict__ y1h, float* __restrict__ hfin)
{
    extern __shared__ __align__(16) uint4 wlds[];      // [LDS_CHUNKS][768]

    const int dir = blockIdx.x & 1;
    const int n   = blockIdx.x >> 1;
    const int t   = threadIdx.x;
    const float* gi  = dir ? giB : giF;
    const float* bhh = dir ? bhhB : bhhF;
    const uint4* wq  = (const uint4*)(dir ? wTB : wTF) + t;

    __shared__ __align__(16) uint32_t h1u[2][HD / 2];  // h as f16x2, dbuf
    __shared__ float s_rz[2 * HD];                     // gi+gh for r,z rows
    __shared__ float s_ghn[HD], s_inn[HD];             // n-row: gh, gi apart

    // stage chunks 0..LDS_CHUNKS-1 (lane-contiguous uint4 rows)
#pragma unroll
    for (int i = 0; i < LDS_CHUNKS; ++i)
        wlds[i * G3 + t] = wq[i * G3];

    const float bh = bhh[t];

    float h_own = 0.0f;
    if (t < HD / 2) h1u[0][t] = 0u;
    __syncthreads();

    const float* gbase = gi + (size_t)n * NSTEP * G3;
    int s = dir ? (NSTEP - 1) : 0;
    float g_own = gbase[s * G3 + t];

    for (int step = 0; step < NSTEP; ++step) {
        const int s_nxt = dir ? (step < NSTEP - 1 ? NSTEP - 2 - step : 0)
                              : (step < NSTEP - 1 ? step + 1 : NSTEP - 1);
        const float g_nxt = gbase[s_nxt * G3 + t];   // hidden under matvec

        const uint32_t* hb = h1u[step & 1];
        float a0 = 0.f, a1 = 0.f, a2 = 0.f, a3 = 0.f;
        // streamed chunks first: long-latency loads issue early
#pragma unroll
        for (int i = LDS_CHUNKS; i < 32; ++i) {
            const uint4 w = wq[i * G3];
            const uint4 hp = *(const uint4*)&hb[4 * i];
            a0 = fdot2u(w.x, hp.x, a0); a1 = fdot2u(w.y, hp.y, a1);
            a2 = fdot2u(w.z, hp.z, a2); a3 = fdot2u(w.w, hp.w, a3);
        }
        // LDS-resident chunks
#pragma unroll
        for (int i = 0; i < LDS_CHUNKS; ++i) {
            const uint4 w = wlds[i * G3 + t];
            const uint4 hp = *(const uint4*)&hb[4 * i];
            a0 = fdot2u(w.x, hp.x, a0); a1 = fdot2u(w.y, hp.y, a1);
            a2 = fdot2u(w.z, hp.z, a2); a3 = fdot2u(w.w, hp.w, a3);
        }
        const float acc = bh + ((a0 + a1) + (a2 + a3));

        if (t < 2 * HD) {
            s_rz[t] = g_own + acc;
        } else {
            s_ghn[t - 2 * HD] = acc;
            s_inn[t - 2 * HD] = g_own;
        }
        __syncthreads();
        if (t < HD) {
            const float r  = sigmf(s_rz[t]);
            const float z  = sigmf(s_rz[HD + t]);
            const float nn = tanhf(s_inn[t] + r * s_ghn[t]);
            const float hnew = (1.0f - z) * nn + z * h_own;
            h_own = hnew;
            const __half hh = __float2half(hnew);
            ((__half*)h1u[(step + 1) & 1])[t] = hh;
            y1h[(size_t)(n * NSTEP + s) * 512 + dir * HD + t] = hh;
        }
        g_own = g_nxt;
        s = s_nxt;
        __syncthreads();
    }
    if (t < HD)
        hfin[(size_t)(dir * NSEQ + n) * HD + t] = h_own;
}

// ---------------- dec_h = w_adj @ [hf,hb] + b_adj ----------------
__global__ __launch_bounds__(256) void adj_kernel(
    const float* __restrict__ hfin, const float* __restrict__ wadjT,
    const float* __restrict__ badj, float* __restrict__ dech)
{
    const int n = blockIdx.x, t = threadIdx.x;
    __shared__ float comb[512];
    comb[t]      = hfin[(size_t)n * HD + t];
    comb[HD + t] = hfin[(size_t)(NSEQ + n) * HD + t];
    __syncthreads();
    float acc = badj[t];
#pragma unroll 8
    for (int f = 0; f < 512; ++f) acc += wadjT[f * HD + t] * comb[f];
    dech[n * HD + t] = acc;
}

// ---------------- decoder: 64 blocks x 768 threads, streamed weights -------
__global__ __launch_bounds__(768, 3) void decoder_kernel(
    const float* __restrict__ dech, const uint32_t* __restrict__ wTd,
    const float* __restrict__ wihdT, const float* __restrict__ bihd,
    const float* __restrict__ bhhd, const float* __restrict__ wfc1T,
    const float* __restrict__ bfc1, float* __restrict__ out)
{
    const int n = blockIdx.x, t = threadIdx.x;
    const uint4* wq = (const uint4*)wTd + t;

    __shared__ __align__(16) uint32_t h1u[2][HD / 2];
    __shared__ float ghs[G3], gis[G3];
    __shared__ float hfp[HD];
    __shared__ float inp[56];
    __shared__ float pf1[448];

    const float bi = bihd[t], bh = bhhd[t];

    float h_own = 0.0f;
    if (t < HD) {
        const float hv = dech[(size_t)n * HD + t];
        h_own = hv;
        ((__half*)h1u[0])[t] = __float2half(hv);
        hfp[t] = hv;
    }
    if (t < 56) inp[t] = 0.0f;
    __syncthreads();

    for (int step = 0; step < 6; ++step) {
        const uint32_t* hb = h1u[step & 1];
        float a0 = 0.f, a1 = 0.f;
#pragma unroll 8
        for (int q = 0; q < 32; ++q) {
            const uint4 w = wq[q * G3];
            const uint4 hp = *(const uint4*)&hb[4 * q];
            a0 = fdot2u(w.x, hp.x, a0); a1 = fdot2u(w.y, hp.y, a1);
            a0 = fdot2u(w.z, hp.z, a0); a1 = fdot2u(w.w, hp.w, a1);
        }
        float ai = bi;
#pragma unroll 8
        for (int v = 0; v < 56; ++v) ai += wihdT[v * G3 + t] * inp[v];
        ghs[t] = a0 + a1 + bh;
        gis[t] = ai;
        __syncthreads();
        if (t < HD) {
            const float r  = sigmf(gis[t] + ghs[t]);
            const float z  = sigmf(gis[HD + t] + ghs[HD + t]);
            const float nn = tanhf(gis[2 * HD + t] + r * ghs[2 * HD + t]);
            const float hnew = (1.0f - z) * nn + z * h_own;
            h_own = hnew;
            ((__half*)h1u[(step + 1) & 1])[t] = __float2half(hnew);
            hfp[t] = hnew;
        }
        __syncthreads();
        if (t < 448) {
            const int v = t >> 3, g = t & 7;
            float o = 0.f;
#pragma unroll
            for (int k2 = 0; k2 < 32; ++k2)
                o += wfc1T[(g * 32 + k2) * 56 + v] * hfp[g * 32 + k2];
            pf1[t] = o;
        }
        __syncthreads();
        if (t < 56) {
            float o = bfc1[t];
#pragma unroll
            for (int g = 0; g < 8; ++g) o += pf1[t * 8 + g];
            out[(size_t)n * 336 + step * 56 + t] = o;
            inp[t] = o;
        }
        __syncthreads();
    }
}

// ---------------------------------------------------------------------------
extern "C" void kernel_launch(void* const* d_in, const int* in_sizes, int n_in,
                              void* d_out, int out_size, void* d_ws, size_t ws_size,
                              hipStream_t stream)
{
    const float* x      = (const float*)d_in[0];
    const float* wih1f  = (const float*)d_in[1];
    const float* whh1f  = (const float*)d_in[2];
    const float* bih1f  = (const float*)d_in[3];
    const float* bhh1f  = (const float*)d_in[4];
    const float* wih1b  = (const float*)d_in[5];
    const float* whh1b  = (const float*)d_in[6];
    const float* bih1b  = (const float*)d_in[7];
    const float* bhh1b  = (const float*)d_in[8];
    const float* wih2f  = (const float*)d_in[9];
    const float* whh2f  = (const float*)d_in[10];
    const float* bih2f  = (const float*)d_in[11];
    const float* bhh2f  = (const float*)d_in[12];
    const float* wih2b  = (const float*)d_in[13];
    const float* whh2b  = (const float*)d_in[14];
    const float* bih2b  = (const float*)d_in[15];
    const float* bhh2b  = (const float*)d_in[16];
    const float* wihd   = (const float*)d_in[17];
    const float* whhd   = (const float*)d_in[18];
    const float* bihd   = (const float*)d_in[19];
    const float* bhhd   = (const float*)d_in[20];
    const float* wfc1   = (const float*)d_in[21];
    const float* bfc1   = (const float*)d_in[22];
    const float* wadj   = (const float*)d_in[23];
    const float* badj   = (const float*)d_in[24];

    float* ws = (float*)d_ws;
    __half*   seqg_h  = (__half*)(ws + 0);           // 786432 f16
    float*    gi_f    = ws + 393216;                 // 3145728
    float*    gi_b    = ws + 3538944;                // 3145728
    __half*   y1h     = (__half*)(ws + 6684672);     // 2097152 f16
    float*    hfin    = ws + 7733248;                // 32768
    float*    dech    = ws + 7766016;                // 16384
    uint32_t* wt1f    = (uint32_t*)(ws + 7782400);   // 98304 each
    uint32_t* wt1b    = (uint32_t*)(ws + 7880704);
    uint32_t* wt2f    = (uint32_t*)(ws + 7979008);
    uint32_t* wt2b    = (uint32_t*)(ws + 8077312);
    uint32_t* wtd     = (uint32_t*)(ws + 8175616);
    __half*   wih1f_h = (__half*)(ws + 8273920);     // 147456 f16
    __half*   wih1b_h = (__half*)(ws + 8347648);
    __half*   wih2f_h = (__half*)(ws + 8421376);     // 393216 f16
    __half*   wih2b_h = (__half*)(ws + 8617984);
    float*    wihdT   = ws + 8814592;                // 43008
    float*    wadjT   = ws + 8857600;                // 131072
    float*    wfc1T   = ws + 8988672;                // 14336

    // allow >64KB dynamic LDS for the scan (160KB/CU on gfx950)
    const int scan_lds = LDS_CHUNKS * G3 * 16;       // 147456 B
    hipFuncSetAttribute((const void*)gru_scan,
                        hipFuncAttributeMaxDynamicSharedMemorySize, scan_lds);

    prep_all<<<5344, 256, 0, stream>>>(
        whh1f, whh1b, whh2f, whh2b, whhd,
        wt1f, wt1b, wt2f, wt2b, wtd,
        wih1f, wih1b, wih2f, wih2b,
        wih1f_h, wih1b_h, wih2f_h, wih2b_h,
        wihd, wadj, wfc1, wihdT, wadjT, wfc1T,
        x, seqg_h);

    // layer 1
    gemm_mfma<<<dim3(64, 12, 2), 256, 0, stream>>>(
        seqg_h, wih1f_h, wih1b_h, bih1f, bih1b, gi_f, gi_b, 192);
    gru_scan<<<128, 768, scan_lds, stream>>>(
        gi_f, gi_b, wt1f, wt1b, bhh1f, bhh1b, y1h, hfin);

    // layer 2 (gi buffers reused; scan2's y1h writes are dead but harmless)
    gemm_mfma<<<dim3(64, 12, 2), 256, 0, stream>>>(
        y1h, wih2f_h, wih2b_h, bih2f, bih2b, gi_f, gi_b, 512);
    gru_scan<<<128, 768, scan_lds, stream>>>(
        gi_f, gi_b, wt2f, wt2b, bhh2f, bhh2b, y1h, hfin);

    // decoder head
    adj_kernel<<<64, 256, 0, stream>>>(hfin, wadjT, badj, dech);
    decoder_kernel<<<64, 768, 0, stream>>>(
        dech, wtd, wihdT, bihd, bhhd, wfc1T, bfc1, (float*)d_out);
}

// Round 13
// 355.543 us; speedup vs baseline: 2.3582x; 1.1504x over previous
//
#include <hip/hip_runtime.h>
#include <hip/hip_fp16.h>
#include <stdint.h>

// ---------------------------------------------------------------------------
// Problem geometry (all compile-time):
//   x: (64, 48, 512, 2, 2) fp32. seq[s,n,f] = x[n, f>>2, 8*s, (f>>1)&1, f&1]
//   (only batch rows n<64 of the 512 matter downstream).
//   Layer1 BiGRU: in=192, H=256, 64 steps. Layer2 BiGRU: in=512, H=256.
//   Only final hiddens of layer2 used. dec_h = w_adj @ [hf,hb] + b_adj.
//   Decoder GRU (in=56, H=256) 6 steps, out = w_fc1@h + b_fc1 -> (64,6,56).
//
// SCAN LEDGER (r2-r12): compiler remats any large resident weight set
// (r2-r10); pure L2 stream = per-CU-port bound 1.3-1.5us/step (r10);
// 64-block variants latency-starve (r11); LDS-staging weights loses because
// h-broadcast ds_reads already saturate the LDS port in the full-K shape
// (r12: 44 LDS instr/thread/step -> 1.9us/step). BEST: r9's split-K hybrid
// (512thr, thread=(kh,tr) owns 3 gate rows x K-half; 6 resident + 10
// streamed chunks; 16 h-reads/thread reused across 3 rows) = 92.8us.
// r13: same structure, 8 resident / 8 streamed (196KB/step from L2).
// Keep r12 infra: merged prep_all (-100us launch overhead), MFMA gemm.
// ---------------------------------------------------------------------------

#define HD 256
#define G3 768
#define NSEQ 64
#define NSTEP 64

typedef _Float16 hvec2 __attribute__((ext_vector_type(2)));
typedef _Float16 f16x8 __attribute__((ext_vector_type(8)));
typedef float f32x4 __attribute__((ext_vector_type(4)));

__device__ __forceinline__ float sigmf(float x) {
    return 1.0f / (1.0f + __expf(-x));
}

#if __has_builtin(__builtin_amdgcn_fdot2)
__device__ __forceinline__ float fdot2u(uint32_t w, uint32_t h, float acc) {
    return __builtin_amdgcn_fdot2(__builtin_bit_cast(hvec2, w),
                                  __builtin_bit_cast(hvec2, h), acc, false);
}
#else
__device__ __forceinline__ float fdot2u(uint32_t w, uint32_t h, float acc) {
    const __half2 wv = __builtin_bit_cast(__half2, w);
    const __half2 hv = __builtin_bit_cast(__half2, h);
    acc += __half2float(wv.x) * __half2float(hv.x);
    acc += __half2float(wv.y) * __half2float(hv.y);
    return acc;
}
#endif

__device__ __forceinline__ uint32_t pkh(float a, float b) {
    uint32_t lo = __half_as_ushort(__float2half_rn(a));
    uint32_t hi = __half_as_ushort(__float2half_rn(b));
    return lo | (hi << 16);
}

#define L8(X) X(0) X(1) X(2) X(3) X(4) X(5) X(6) X(7)

// resident chunks: 8 per gate row (of 16 per K-half) = 24 uint4 = 96 dwords
#define LRES(i) \
    const uint4 wr##i = wbase[(i) * G3]; \
    const uint4 wz##i = wbase[(i) * G3 + 256]; \
    const uint4 wn##i = wbase[(i) * G3 + 512];

#define DRES(i) { \
    const uint4 hp = *(const uint4*)&hb[hoff + 4 * (i)]; \
    ar0 = fdot2u(wr##i.x, hp.x, ar0); ar1 = fdot2u(wr##i.y, hp.y, ar1); \
    ar0 = fdot2u(wr##i.z, hp.z, ar0); ar1 = fdot2u(wr##i.w, hp.w, ar1); \
    az0 = fdot2u(wz##i.x, hp.x, az0); az1 = fdot2u(wz##i.y, hp.y, az1); \
    az0 = fdot2u(wz##i.z, hp.z, az0); az1 = fdot2u(wz##i.w, hp.w, az1); \
    an0 = fdot2u(wn##i.x, hp.x, an0); an1 = fdot2u(wn##i.y, hp.y, an1); \
    an0 = fdot2u(wn##i.z, hp.z, an0); an1 = fdot2u(wn##i.w, hp.w, an1); }

// ---------------- merged weight/input prep (one launch) ----------------
// Block ranges:
//   [0,480)      pack Whh (5 tensors x 96 blocks)
//   [480,768)    wih1f/wih1b fp32->f16 (144 blocks each)
//   [768,1536)   wih2f/wih2b fp32->f16 (384 blocks each)
//   [1536,2272)  small transposes (736)
//   [2272,5344)  gather seq -> f16 (3072)
__global__ __launch_bounds__(256) void prep_all(
    const float* __restrict__ whh1f, const float* __restrict__ whh1b,
    const float* __restrict__ whh2f, const float* __restrict__ whh2b,
    const float* __restrict__ whhd,
    uint32_t* __restrict__ wt1f, uint32_t* __restrict__ wt1b,
    uint32_t* __restrict__ wt2f, uint32_t* __restrict__ wt2b,
    uint32_t* __restrict__ wtd,
    const float* __restrict__ wih1f, const float* __restrict__ wih1b,
    const float* __restrict__ wih2f, const float* __restrict__ wih2b,
    __half* __restrict__ wih1f_h, __half* __restrict__ wih1b_h,
    __half* __restrict__ wih2f_h, __half* __restrict__ wih2b_h,
    const float* __restrict__ wihd, const float* __restrict__ wadj,
    const float* __restrict__ wfc1,
    float* __restrict__ wihdT, float* __restrict__ wadjT,
    float* __restrict__ wfc1T,
    const float* __restrict__ x, __half* __restrict__ seqg)
{
    const int b   = blockIdx.x;
    const int tid = threadIdx.x;

    if (b < 480) {
        // Whh repack -> uint4[q*768 + j], q=0..31 holds k=8q..8q+7 of row j
        const int y = b / 96;
        const float* w; uint32_t* o;
        switch (y) {
            case 0: w = whh1f; o = wt1f; break;
            case 1: w = whh1b; o = wt1b; break;
            case 2: w = whh2f; o = wt2f; break;
            case 3: w = whh2b; o = wt2b; break;
            default: w = whhd; o = wtd; break;
        }
        const int idx = (b % 96) * 256 + tid;   // 24576
        const int j = idx >> 5, q = idx & 31;
        const float4 fa = *(const float4*)(w + j * HD + 8 * q);
        const float4 fb = *(const float4*)(w + j * HD + 8 * q + 4);
        uint4 r;
        r.x = pkh(fa.x, fa.y); r.y = pkh(fa.z, fa.w);
        r.z = pkh(fb.x, fb.y); r.w = pkh(fb.z, fb.w);
        ((uint4*)o)[q * G3 + j] = r;
    } else if (b < 1536) {
        const float* s; __half* d; int i4;
        if (b < 624)       { s = wih1f; d = wih1f_h; i4 = (b - 480) * 256 + tid; }
        else if (b < 768)  { s = wih1b; d = wih1b_h; i4 = (b - 624) * 256 + tid; }
        else if (b < 1152) { s = wih2f; d = wih2f_h; i4 = (b - 768) * 256 + tid; }
        else               { s = wih2b; d = wih2b_h; i4 = (b - 1152) * 256 + tid; }
        const float4 v = *(const float4*)(s + (size_t)i4 * 4);
        __half2 lo; lo.x = __float2half_rn(v.x); lo.y = __float2half_rn(v.y);
        __half2 hi; hi.x = __float2half_rn(v.z); hi.y = __float2half_rn(v.w);
        *(__half2*)(d + (size_t)i4 * 4)     = lo;
        *(__half2*)(d + (size_t)i4 * 4 + 2) = hi;
    } else if (b < 2272) {
        const int idx = (b - 1536) * 256 + tid;  // 188416
        if (idx < 43008) {
            int v = idx / G3, j = idx % G3;
            wihdT[idx] = wihd[j * 56 + v];
        } else if (idx < 43008 + 131072) {
            int i2 = idx - 43008;
            int f = i2 / HD, i = i2 % HD;
            wadjT[i2] = wadj[i * 512 + f];
        } else {
            int i3 = idx - 174080;
            int k = i3 / 56, v = i3 % 56;
            wfc1T[i3] = wfc1[v * HD + k];
        }
    } else {
        const int idx = (b - 2272) * 256 + tid;  // 786432
        const int f = idx % 192;
        const int m = idx / 192;
        const int n = m >> 6, s = m & 63;
        seqg[idx] = __float2half(
            x[n * 98304 + (f >> 2) * 2048 + s * 32 + (f & 3)]);
    }
}

// ---------------- f16 MFMA GEMM with bias ----------------
// C[m][j] = sum_k A[m][k]*B[j][k] + bias[j]; M=4096, N=768, K in {192,512}.
// grid=(64, 12, 2); block = 4 waves; wave w computes rows m0+16w..+16,
// cols n0..n0+63 as 4 accumulators. No LDS: operands are L2-resident.
// C/D layout (HW-verified): col=lane&15, row=(lane>>4)*4+reg.
__global__ __launch_bounds__(256) void gemm_mfma(
    const __half* __restrict__ A,
    const __half* __restrict__ B0, const __half* __restrict__ B1,
    const float* __restrict__ bias0, const float* __restrict__ bias1,
    float* __restrict__ C0, float* __restrict__ C1, int K)
{
    const __half* B    = blockIdx.z ? B1 : B0;
    const float*  bias = blockIdx.z ? bias1 : bias0;
    float*        C    = blockIdx.z ? C1 : C0;
    const int m0 = blockIdx.x * 64;
    const int n0 = blockIdx.y * 64;
    const int w  = threadIdx.x >> 6;
    const int l  = threadIdx.x & 63;
    const int lr = l & 15;
    const int lk = (l >> 4) * 8;

    const __half* arow = A + (size_t)(m0 + w * 16 + lr) * K + lk;
    const __half* brow = B + (size_t)(n0 + lr) * K + lk;

    f32x4 acc0 = {0.f, 0.f, 0.f, 0.f};
    f32x4 acc1 = acc0, acc2 = acc0, acc3 = acc0;

#pragma unroll 2
    for (int k0 = 0; k0 < K; k0 += 32) {
        const f16x8 a  = *(const f16x8*)(arow + k0);
        const f16x8 b0 = *(const f16x8*)(brow + k0);
        const f16x8 b1 = *(const f16x8*)(brow + 16 * K + k0);
        const f16x8 b2 = *(const f16x8*)(brow + 32 * K + k0);
        const f16x8 b3 = *(const f16x8*)(brow + 48 * K + k0);
        acc0 = __builtin_amdgcn_mfma_f32_16x16x32_f16(a, b0, acc0, 0, 0, 0);
        acc1 = __builtin_amdgcn_mfma_f32_16x16x32_f16(a, b1, acc1, 0, 0, 0);
        acc2 = __builtin_amdgcn_mfma_f32_16x16x32_f16(a, b2, acc2, 0, 0, 0);
        acc3 = __builtin_amdgcn_mfma_f32_16x16x32_f16(a, b3, acc3, 0, 0, 0);
    }

    const int crow = m0 + w * 16 + (l >> 4) * 4;
    const int ccol = n0 + lr;
    float* cp = C + (size_t)crow * G3 + ccol;
    const float bb0 = bias[ccol];
    const float bb1 = bias[ccol + 16];
    const float bb2 = bias[ccol + 32];
    const float bb3 = bias[ccol + 48];
#pragma unroll
    for (int j = 0; j < 4; ++j) {
        cp[(size_t)j * G3 +  0] = acc0[j] + bb0;
        cp[(size_t)j * G3 + 16] = acc1[j] + bb1;
        cp[(size_t)j * G3 + 32] = acc2[j] + bb2;
        cp[(size_t)j * G3 + 48] = acc3[j] + bb3;
    }
}

// ---------------- hybrid resident/streamed GRU scan (split-K, 512 thr) -----
// grid = 128 blocks: dir = blockIdx.x&1, n = blockIdx.x>>1.
// Thread (kh=t>>8, tr=t&255): gate rows {tr,256+tr,512+tr}, K-half kh.
// Chunks 0..7 of each gate row resident (96 dwords); chunks 8..15 streamed
// from L2 every step (196KB/step). Idle kh==1 half prefetches gi into LDS.
// h-reads: 16 uint4/thread/step, each reused across 3 gate rows (the
// LDS-port-cheap shape — r12 lesson).
__global__ __launch_bounds__(512, 1) void gru_scan(
    const float* __restrict__ giF, const float* __restrict__ giB,
    const uint32_t* __restrict__ wTF, const uint32_t* __restrict__ wTB,
    const float* __restrict__ bhhF, const float* __restrict__ bhhB,
    __half* __restrict__ y1h, float* __restrict__ hfin)
{
    const int dir = blockIdx.x & 1;
    const int n   = blockIdx.x >> 1;
    const int t   = threadIdx.x;
    const int tr  = t & 255;
    const int kh  = t >> 8;
    const int hoff = kh * 64;        // u32 offset into h buffer
    const float* gi  = dir ? giB : giF;
    const float* bhh = dir ? bhhB : bhhF;
    const uint4* wbase = (const uint4*)(dir ? wTB : wTF) + (size_t)(kh * 16) * G3 + tr;

    __shared__ __align__(16) uint32_t h1u[2][HD / 2];  // h as f16x2, dbuf
    __shared__ float ph_r[HD], ph_z[HD], ph_n[HD];     // upper-half partials
    __shared__ float gin[2][G3];                       // gi double buffer

    L8(LRES)
    const float bhr = bhh[tr], bhz = bhh[256 + tr], bhn = bhh[512 + tr];

    const float* gbase = gi + (size_t)n * NSTEP * G3;
    const int s0 = dir ? (NSTEP - 1) : 0;
#pragma unroll
    for (int i = t; i < G3; i += 512) gin[0][i] = gbase[s0 * G3 + i];

    float h_own = 0.0f;
    if (t < HD / 2) h1u[0][t] = 0u;
    __syncthreads();

    int s = s0;
    for (int step = 0; step < NSTEP; ++step) {
        const uint32_t* hb = h1u[step & 1];
        float ar0 = 0.f, ar1 = 0.f;
        float az0 = 0.f, az1 = 0.f;
        float an0 = 0.f, an1 = 0.f;
        L8(DRES)
#pragma unroll
        for (int i = 8; i < 16; ++i) {
            const uint4 sr = wbase[i * G3];
            const uint4 sz = wbase[i * G3 + 256];
            const uint4 sn = wbase[i * G3 + 512];
            const uint4 hp = *(const uint4*)&hb[hoff + 4 * i];
            ar0 = fdot2u(sr.x, hp.x, ar0); ar1 = fdot2u(sr.y, hp.y, ar1);
            ar0 = fdot2u(sr.z, hp.z, ar0); ar1 = fdot2u(sr.w, hp.w, ar1);
            az0 = fdot2u(sz.x, hp.x, az0); az1 = fdot2u(sz.y, hp.y, az1);
            az0 = fdot2u(sz.z, hp.z, az0); az1 = fdot2u(sz.w, hp.w, az1);
            an0 = fdot2u(sn.x, hp.x, an0); an1 = fdot2u(sn.y, hp.y, an1);
            an0 = fdot2u(sn.z, hp.z, an0); an1 = fdot2u(sn.w, hp.w, an1);
        }

        if (kh) {
            ph_r[tr] = ar0 + ar1;
            ph_z[tr] = az0 + az1;
            ph_n[tr] = an0 + an1;
        }
        __syncthreads();
        const int s_nxt = dir ? (step < NSTEP - 1 ? NSTEP - 2 - step : 0)
                              : (step < NSTEP - 1 ? step + 1 : NSTEP - 1);
        if (kh == 0) {
            const float* gcur = gin[step & 1];
            const float ghr = (ar0 + ar1) + ph_r[tr] + bhr;
            const float ghz = (az0 + az1) + ph_z[tr] + bhz;
            const float ghn = (an0 + an1) + ph_n[tr] + bhn;
            const float r  = sigmf(gcur[tr] + ghr);
            const float z  = sigmf(gcur[256 + tr] + ghz);
            const float nn = tanhf(gcur[512 + tr] + r * ghn);
            const float hnew = (1.0f - z) * nn + z * h_own;
            h_own = hnew;
            const __half hh = __float2half(hnew);
            ((__half*)h1u[(step + 1) & 1])[tr] = hh;
            y1h[(size_t)(n * NSTEP + s) * 512 + dir * HD + tr] = hh;
        } else {
            float* gnxt = gin[(step + 1) & 1];
#pragma unroll
            for (int i = tr; i < G3; i += 256)
                gnxt[i] = gbase[s_nxt * G3 + i];
        }
        s = s_nxt;
        __syncthreads();
    }
    if (kh == 0)
        hfin[(size_t)(dir * NSEQ + n) * HD + tr] = h_own;
}

// ---------------- dec_h = w_adj @ [hf,hb] + b_adj ----------------
__global__ __launch_bounds__(256) void adj_kernel(
    const float* __restrict__ hfin, const float* __restrict__ wadjT,
    const float* __restrict__ badj, float* __restrict__ dech)
{
    const int n = blockIdx.x, t = threadIdx.x;
    __shared__ float comb[512];
    comb[t]      = hfin[(size_t)n * HD + t];
    comb[HD + t] = hfin[(size_t)(NSEQ + n) * HD + t];
    __syncthreads();
    float acc = badj[t];
#pragma unroll 8
    for (int f = 0; f < 512; ++f) acc += wadjT[f * HD + t] * comb[f];
    dech[n * HD + t] = acc;
}

// ---------------- decoder: 64 blocks x 768 threads, streamed weights -------
__global__ __launch_bounds__(768, 3) void decoder_kernel(
    const float* __restrict__ dech, const uint32_t* __restrict__ wTd,
    const float* __restrict__ wihdT, const float* __restrict__ bihd,
    const float* __restrict__ bhhd, const float* __restrict__ wfc1T,
    const float* __restrict__ bfc1, float* __restrict__ out)
{
    const int n = blockIdx.x, t = threadIdx.x;
    const uint4* wq = (const uint4*)wTd + t;

    __shared__ __align__(16) uint32_t h1u[2][HD / 2];
    __shared__ float ghs[G3], gis[G3];
    __shared__ float hfp[HD];
    __shared__ float inp[56];
    __shared__ float pf1[448];

    const float bi = bihd[t], bh = bhhd[t];

    float h_own = 0.0f;
    if (t < HD) {
        const float hv = dech[(size_t)n * HD + t];
        h_own = hv;
        ((__half*)h1u[0])[t] = __float2half(hv);
        hfp[t] = hv;
    }
    if (t < 56) inp[t] = 0.0f;
    __syncthreads();

    for (int step = 0; step < 6; ++step) {
        const uint32_t* hb = h1u[step & 1];
        float a0 = 0.f, a1 = 0.f;
#pragma unroll 8
        for (int q = 0; q < 32; ++q) {
            const uint4 w = wq[q * G3];
            const uint4 hp = *(const uint4*)&hb[4 * q];
            a0 = fdot2u(w.x, hp.x, a0); a1 = fdot2u(w.y, hp.y, a1);
            a0 = fdot2u(w.z, hp.z, a0); a1 = fdot2u(w.w, hp.w, a1);
        }
        float ai = bi;
#pragma unroll 8
        for (int v = 0; v < 56; ++v) ai += wihdT[v * G3 + t] * inp[v];
        ghs[t] = a0 + a1 + bh;
        gis[t] = ai;
        __syncthreads();
        if (t < HD) {
            const float r  = sigmf(gis[t] + ghs[t]);
            const float z  = sigmf(gis[HD + t] + ghs[HD + t]);
            const float nn = tanhf(gis[2 * HD + t] + r * ghs[2 * HD + t]);
            const float hnew = (1.0f - z) * nn + z * h_own;
            h_own = hnew;
            ((__half*)h1u[(step + 1) & 1])[t] = __float2half(hnew);
            hfp[t] = hnew;
        }
        __syncthreads();
        if (t < 448) {
            const int v = t >> 3, g = t & 7;
            float o = 0.f;
#pragma unroll
            for (int k2 = 0; k2 < 32; ++k2)
                o += wfc1T[(g * 32 + k2) * 56 + v] * hfp[g * 32 + k2];
            pf1[t] = o;
        }
        __syncthreads();
        if (t < 56) {
            float o = bfc1[t];
#pragma unroll
            for (int g = 0; g < 8; ++g) o += pf1[t * 8 + g];
            out[(size_t)n * 336 + step * 56 + t] = o;
            inp[t] = o;
        }
        __syncthreads();
    }
}

// ---------------------------------------------------------------------------
extern "C" void kernel_launch(void* const* d_in, const int* in_sizes, int n_in,
                              void* d_out, int out_size, void* d_ws, size_t ws_size,
                              hipStream_t stream)
{
    const float* x      = (const float*)d_in[0];
    const float* wih1f  = (const float*)d_in[1];
    const float* whh1f  = (const float*)d_in[2];
    const float* bih1f  = (const float*)d_in[3];
    const float* bhh1f  = (const float*)d_in[4];
    const float* wih1b  = (const float*)d_in[5];
    const float* whh1b  = (const float*)d_in[6];
    const float* bih1b  = (const float*)d_in[7];
    const float* bhh1b  = (const float*)d_in[8];
    const float* wih2f  = (const float*)d_in[9];
    const float* whh2f  = (const float*)d_in[10];
    const float* bih2f  = (const float*)d_in[11];
    const float* bhh2f  = (const float*)d_in[12];
    const float* wih2b  = (const float*)d_in[13];
    const float* whh2b  = (const float*)d_in[14];
    const float* bih2b  = (const float*)d_in[15];
    const float* bhh2b  = (const float*)d_in[16];
    const float* wihd   = (const float*)d_in[17];
    const float* whhd   = (const float*)d_in[18];
    const float* bihd   = (const float*)d_in[19];
    const float* bhhd   = (const float*)d_in[20];
    const float* wfc1   = (const float*)d_in[21];
    const float* bfc1   = (const float*)d_in[22];
    const float* wadj   = (const float*)d_in[23];
    const float* badj   = (const float*)d_in[24];

    float* ws = (float*)d_ws;
    __half*   seqg_h  = (__half*)(ws + 0);           // 786432 f16
    float*    gi_f    = ws + 393216;                 // 3145728
    float*    gi_b    = ws + 3538944;                // 3145728
    __half*   y1h     = (__half*)(ws + 6684672);     // 2097152 f16
    float*    hfin    = ws + 7733248;                // 32768
    float*    dech    = ws + 7766016;                // 16384
    uint32_t* wt1f    = (uint32_t*)(ws + 7782400);   // 98304 each
    uint32_t* wt1b    = (uint32_t*)(ws + 7880704);
    uint32_t* wt2f    = (uint32_t*)(ws + 7979008);
    uint32_t* wt2b    = (uint32_t*)(ws + 8077312);
    uint32_t* wtd     = (uint32_t*)(ws + 8175616);
    __half*   wih1f_h = (__half*)(ws + 8273920);     // 147456 f16
    __half*   wih1b_h = (__half*)(ws + 8347648);
    __half*   wih2f_h = (__half*)(ws + 8421376);     // 393216 f16
    __half*   wih2b_h = (__half*)(ws + 8617984);
    float*    wihdT   = ws + 8814592;                // 43008
    float*    wadjT   = ws + 8857600;                // 131072
    float*    wfc1T   = ws + 8988672;                // 14336

    prep_all<<<5344, 256, 0, stream>>>(
        whh1f, whh1b, whh2f, whh2b, whhd,
        wt1f, wt1b, wt2f, wt2b, wtd,
        wih1f, wih1b, wih2f, wih2b,
        wih1f_h, wih1b_h, wih2f_h, wih2b_h,
        wihd, wadj, wfc1, wihdT, wadjT, wfc1T,
        x, seqg_h);

    // layer 1
    gemm_mfma<<<dim3(64, 12, 2), 256, 0, stream>>>(
        seqg_h, wih1f_h, wih1b_h, bih1f, bih1b, gi_f, gi_b, 192);
    gru_scan<<<128, 512, 0, stream>>>(
        gi_f, gi_b, wt1f, wt1b, bhh1f, bhh1b, y1h, hfin);

    // layer 2 (gi buffers reused; scan2's y1h writes are dead but harmless)
    gemm_mfma<<<dim3(64, 12, 2), 256, 0, stream>>>(
        y1h, wih2f_h, wih2b_h, bih2f, bih2b, gi_f, gi_b, 512);
    gru_scan<<<128, 512, 0, stream>>>(
        gi_f, gi_b, wt2f, wt2b, bhh2f, bhh2b, y1h, hfin);

    // decoder head
    adj_kernel<<<64, 256, 0, stream>>>(hfin, wadjT, badj, dech);
    decoder_kernel<<<64, 768, 0, stream>>>(
        dech, wtd, wihdT, bihd, bhhd, wfc1T, bfc1, (float*)d_out);
}